// Round 10
// baseline (39579.538 us; speedup 1.0000x reference)
//
#include <hip/hip_runtime.h>
#include <hip/hip_cooperative_groups.h>

namespace cg = cooperative_groups;

// HyperLSTM + MDN decoder — f32 in / f32 out (verified R5/R6/R8, absmax 7.8e-3).
// R10: R9's LDS-tiled persistent kernel + fix of the tail-step fall-through
// (at t==NSEQ blocks 0..175 fell into the proj branch with negative c0 and
// sprayed tanh(garbage) over the corr_xy out-region; branch dispatch is now
// purely blockIdx-based, t-guards inside).
#define NSEQ 128

__device__ float g_hT  [1024 * 64];
__device__ float g_cT  [1024 * 64];
__device__ float g_hhT [256 * 64];
__device__ float g_chT0[256 * 64];
__device__ float g_chT1[256 * 64];
__device__ float g_gP  [3 * 1024 * 64];   // gate partials (3 k-parts)
__device__ float g_hWhP[2 * 4096 * 64];   // hWh partials (2 k-halves)
__device__ float g_xWxT[4096 * 64];
__device__ float g_zT  [768 * 64];        // zx|zh|zb
__device__ float g_xT  [133 * 64];
__device__ float g_penT[3 * 64];

__device__ __forceinline__ float sigf(float x) { return 1.0f / (1.0f + expf(-x)); }

// Tiled GEMV accumulate: out cols wcolbase..+63 (8/thread), k-tiles of 64.
// Stages W and act 64x64 tiles in LDS; W reads broadcast, act reads b-coalesced.
__device__ __forceinline__ void gemv_chunks(
    const float* __restrict__ W, int ldw, int wrow0, int wcolbase, int ncols,
    int actsel, int aoff, int len, float acc[8],
    float* ldsW, float* ldsA,
    const float* __restrict__ xT, const float* __restrict__ hT,
    const float* __restrict__ hhT, int b, int cw, int tid)
{
    for (int k0 = 0; k0 < len; k0 += 64) {
        int cs = (len - k0 < 64) ? (len - k0) : 64;
        __syncthreads();
        for (int i = tid; i < cs * 64; i += 512) {
            int kk = i >> 6, cl = i & 63;
            ldsW[i] = (cl < ncols) ? W[(wrow0 + k0 + kk) * ldw + wcolbase + cl] : 0.f;
            int u = aoff + k0 + kk;
            float av;
            if      (actsel == 0) av = xT[u * 64 + cl];
            else if (actsel == 1) av = hT[u * 64 + cl];
            else if (actsel == 2) av = hhT[u * 64 + cl];
            else av = (u < 133) ? xT[u * 64 + cl] : hT[(u - 133) * 64 + cl];
            ldsA[i] = av;
        }
        __syncthreads();
        #pragma unroll 4
        for (int kk = 0; kk < cs; kk++) {
            float av = ldsA[kk * 64 + b];
            #pragma unroll
            for (int j = 0; j < 8; j++)
                acc[j] += av * ldsW[kk * 64 + cw * 8 + j];
        }
    }
}

__global__ __launch_bounds__(512, 2) void mega_kernel(
    const float* __restrict__ z,        const float* __restrict__ strokes,
    const float* __restrict__ fc_in_w,  const float* __restrict__ fc_in_b,
    const float* __restrict__ fc_proj_w,const float* __restrict__ fc_proj_b,
    const float* __restrict__ Wx,       const float* __restrict__ Wh,
    const float* __restrict__ b0w,
    const float* __restrict__ Wxh_hy,   const float* __restrict__ Whh_hy,
    const float* __restrict__ b_hy,
    const float* __restrict__ Wzx,      const float* __restrict__ bzx,
    const float* __restrict__ Wzh,      const float* __restrict__ bzh,
    const float* __restrict__ Wzb,
    const float* __restrict__ Dx,       const float* __restrict__ Dh,
    const float* __restrict__ Db,       float* __restrict__ out)
{
    cg::grid_group grid = cg::this_grid();
    const int blk = blockIdx.x, tid = threadIdx.x;
    const int b = tid & 63, cw = tid >> 6;

    __shared__ float ldsW[4096];
    __shared__ float ldsA[4096];
    __shared__ float ldsD[1024];

    // ================= init: s0 = tanh(z @ fc_in_w + b) =================
    for (int i = tid; i < 8192; i += 512) {
        float v = z[(i & 63) * 128 + (i >> 6)];
        if (i < 4096) ldsW[i] = v; else ldsA[i - 4096] = v;
    }
    __syncthreads();
    for (int n = tid; n < 640; n += 512) {
        int item = blk * 640 + n, j = item >> 6, bb = item & 63;
        float acc = fc_in_b[j];
        #pragma unroll 4
        for (int k = 0; k < 128; k++) {
            float zv = (k < 64) ? ldsW[k * 64 + bb] : ldsA[(k - 64) * 64 + bb];
            acc += zv * fc_in_w[k * 2560 + j];
        }
        float s = tanhf(acc);
        if      (j < 1024) g_hT  [j * 64 + bb]          = s;
        else if (j < 2048) g_cT  [(j - 1024) * 64 + bb] = s;
        else if (j < 2304) g_hhT [(j - 2048) * 64 + bb] = s;
        else               g_chT0[(j - 2304) * 64 + bb] = s;
    }
    if (blk >= 224 && blk < 241) {
        int idx = (blk - 224) * 512 + tid;
        if (idx < 8512) g_xT[idx] = strokes[(idx & 63) * 133 + (idx >> 6)];
    }
    grid.sync();

    // ================= main loop =================
    for (int t = 0; t <= NSEQ; t++) {
        const float* chS = (t & 1) ? g_chT1 : g_chT0;
        float*       chD = (t & 1) ? g_chT0 : g_chT1;

        // ---------------- S1 (branch purely on blk; t-guards inside) -------
        if (blk < 128) {                              // Wh halves
            if (t < NSEQ) {
                int c0 = (blk & 63) * 64, kh = blk >> 6;
                float acc[8] = {0,0,0,0,0,0,0,0};
                gemv_chunks(Wh, 4096, kh * 512, c0, 64, 1, kh * 512, 512,
                            acc, ldsW, ldsA, g_xT, g_hT, g_hhT, b, cw, tid);
                #pragma unroll
                for (int j = 0; j < 8; j++)
                    g_hWhP[kh * 262144 + (c0 + cw * 8 + j) * 64 + b] = acc[j];
            }
        } else if (blk < 176) {                       // gates, 16 tiles x 3 parts
            if (t < NSEQ) {
                int gt = (blk - 128) / 3, part = (blk - 128) % 3;
                int gc0 = gt * 64;
                float acc[8] = {0,0,0,0,0,0,0,0};
                if (part == 0)
                    gemv_chunks(Wxh_hy, 1024, 0, gc0, 64, 3, 0, 471,
                                acc, ldsW, ldsA, g_xT, g_hT, g_hhT, b, cw, tid);
                else if (part == 1)
                    gemv_chunks(Wxh_hy, 1024, 471, gc0, 64, 1, 338, 471,
                                acc, ldsW, ldsA, g_xT, g_hT, g_hhT, b, cw, tid);
                else {
                    gemv_chunks(Wxh_hy, 1024, 942, gc0, 64, 1, 809, 215,
                                acc, ldsW, ldsA, g_xT, g_hT, g_hhT, b, cw, tid);
                    gemv_chunks(Whh_hy, 1024, 0, gc0, 64, 2, 0, 256,
                                acc, ldsW, ldsA, g_xT, g_hT, g_hhT, b, cw, tid);
                }
                #pragma unroll
                for (int j = 0; j < 8; j++)
                    g_gP[part * 65536 + (gc0 + cw * 8 + j) * 64 + b] = acc[j];
            }
        } else if (blk < 178) {                       // proj for t-1
            if (t > 0) {
                int c0 = (blk - 176) * 64;
                int ncols = (blk == 176) ? 64 : 59;
                float acc[8] = {0,0,0,0,0,0,0,0};
                gemv_chunks(fc_proj_w, 123, 0, c0, ncols, 1, 0, 1024,
                            acc, ldsW, ldsA, g_xT, g_hT, g_hhT, b, cw, tid);
                int tp = t - 1;
                #pragma unroll
                for (int j = 0; j < 8; j++) {
                    int col = c0 + cw * 8 + j;
                    if (col < 123) {
                        float acv = acc[j] + fc_proj_b[col];
                        if (col < 120) {
                            int m = col / 6, jj = col - m * 6;
                            int oidx = tp * 1280 + m * 64 + b;
                            if      (jj == 0) out[oidx]          = 1.0f;
                            else if (jj == 1) out[163840 + oidx] = acv;
                            else if (jj == 2) out[327680 + oidx] = acv;
                            else if (jj == 3) out[491520 + oidx] = expf(acv);
                            else if (jj == 4) out[655360 + oidx] = expf(acv);
                            else              out[819200 + oidx] = tanhf(acv);
                        } else {
                            g_penT[(col - 120) * 64 + b] = acv;
                        }
                    }
                }
            }
        } else if (blk < 242) {                       // xWx, 64 tiles
            if (t < NSEQ) {
                int c0 = (blk - 178) * 64;
                float acc[8] = {0,0,0,0,0,0,0,0};
                gemv_chunks(Wx, 4096, 0, c0, 64, 0, 0, 133,
                            acc, ldsW, ldsA, g_xT, g_hT, g_hhT, b, cw, tid);
                #pragma unroll
                for (int j = 0; j < 8; j++)
                    g_xWxT[(c0 + cw * 8 + j) * 64 + b] = acc[j];
            }
        }
        grid.sync();   // s1

        // ---------------- S2 ----------------
        if (t > 0 && blk == 100 && tid < 64) {        // pen softmax (t-1)
            float v0 = g_penT[b], v1 = g_penT[64 + b], v2 = g_penT[128 + b];
            float mx = fmaxf(v0, fmaxf(v1, v2));
            float e0 = expf(v0 - mx), e1 = expf(v1 - mx), e2 = expf(v2 - mx);
            float s = e0 + e1 + e2;
            int base = 983040 + (t - 1) * 192 + b * 3;
            out[base] = e0 / s; out[base + 1] = e1 / s; out[base + 2] = e2 / s;
        }
        if (t == NSEQ) break;

        if (blk < 12) {                               // z tiles (recompute hh')
            int zc0 = blk * 64;
            const float* Wsel = (zc0 < 256) ? Wzx : (zc0 < 512) ? Wzh : Wzb;
            int colbase = zc0 & 255;
            float acc[8] = {0,0,0,0,0,0,0,0};
            for (int chunk = 0; chunk < 4; chunk++) {
                __syncthreads();
                for (int i = tid; i < 4096; i += 512) {
                    int kk = i >> 6, bb = i & 63, f = chunk * 64 + kk;
                    float gi = g_gP[f * 64 + bb] + g_gP[65536 + f * 64 + bb]
                             + g_gP[131072 + f * 64 + bb] + b_hy[f];
                    float gf = g_gP[(256 + f) * 64 + bb] + g_gP[65536 + (256 + f) * 64 + bb]
                             + g_gP[131072 + (256 + f) * 64 + bb] + b_hy[256 + f];
                    float gg = g_gP[(512 + f) * 64 + bb] + g_gP[65536 + (512 + f) * 64 + bb]
                             + g_gP[131072 + (512 + f) * 64 + bb] + b_hy[512 + f];
                    float go = g_gP[(768 + f) * 64 + bb] + g_gP[65536 + (768 + f) * 64 + bb]
                             + g_gP[131072 + (768 + f) * 64 + bb] + b_hy[768 + f];
                    float chv = chS[f * 64 + bb];
                    float nc = sigf(gf) * chv + sigf(gi) * tanhf(gg);
                    ldsA[i] = sigf(go) * tanhf(nc);
                }
                for (int i = tid; i < 4096; i += 512) {
                    int kk = i >> 6, cl = i & 63, f = chunk * 64 + kk;
                    ldsW[i] = Wsel[f * 256 + colbase + cl];
                }
                __syncthreads();
                #pragma unroll 4
                for (int kk = 0; kk < 64; kk++) {
                    float av = ldsA[kk * 64 + b];
                    #pragma unroll
                    for (int j = 0; j < 8; j++)
                        acc[j] += av * ldsW[kk * 64 + cw * 8 + j];
                }
            }
            #pragma unroll
            for (int j = 0; j < 8; j++) {
                int zc = zc0 + cw * 8 + j;
                float bias = (zc < 256) ? bzx[zc] : (zc < 512) ? bzh[zc - 256] : 0.f;
                g_zT[zc * 64 + b] = acc[j] + bias;
            }
        } else if (blk >= 32 && blk < 64) {           // canonical hh/ch update
            int item = (blk - 32) * 512 + tid, f = item >> 6, bb = item & 63;
            float gi = g_gP[f * 64 + bb] + g_gP[65536 + f * 64 + bb]
                     + g_gP[131072 + f * 64 + bb] + b_hy[f];
            float gf = g_gP[(256 + f) * 64 + bb] + g_gP[65536 + (256 + f) * 64 + bb]
                     + g_gP[131072 + (256 + f) * 64 + bb] + b_hy[256 + f];
            float gg = g_gP[(512 + f) * 64 + bb] + g_gP[65536 + (512 + f) * 64 + bb]
                     + g_gP[131072 + (512 + f) * 64 + bb] + b_hy[512 + f];
            float go = g_gP[(768 + f) * 64 + bb] + g_gP[65536 + (768 + f) * 64 + bb]
                     + g_gP[131072 + (768 + f) * 64 + bb] + b_hy[768 + f];
            float chv = chS[f * 64 + bb];
            float nc = sigf(gf) * chv + sigf(gi) * tanhf(gg);
            float nh = sigf(go) * tanhf(nc);
            chD[f * 64 + bb] = nc;
            g_hhT[f * 64 + bb] = nh;
        } else if (blk >= 224 && blk < 241 && t + 1 < NSEQ) {   // x(t+1)
            int idx = (blk - 224) * 512 + tid;
            if (idx < 8512)
                g_xT[idx] = strokes[((t + 1) * 64 + (idx & 63)) * 133 + (idx >> 6)];
        }
        grid.sync();   // s2

        // ---------------- S3: einsums + combine + c/h update ----------------
        if (blk < 64) {
            int h0 = blk * 16, hs = tid >> 6;
            float pr[4][2];
            #pragma unroll
            for (int g = 0; g < 4; g++) {
                float s0[2] = {0.f, 0.f}, s1[2] = {0.f, 0.f}, s2[2] = {0.f, 0.f};
                #pragma unroll
                for (int tt = 0; tt < 3; tt++) {
                    const float* Dt = (tt == 0) ? Dx : (tt == 1) ? Dh : Db;
                    __syncthreads();
                    for (int i = tid; i < 4096; i += 512) {
                        int kk = i >> 6, bb = i & 63;
                        ldsA[i] = g_zT[(tt * 256 + g * 64 + kk) * 64 + bb];
                    }
                    for (int i = tid; i < 1024; i += 512) {
                        int f = i >> 4, hl = i & 15;
                        ldsD[i] = Dt[(g * 64 + f) * 1024 + h0 + hl];
                    }
                    __syncthreads();
                    float a0 = 0.f, a1 = 0.f;
                    #pragma unroll 4
                    for (int f = 0; f < 64; f++) {
                        float zv = ldsA[f * 64 + b];
                        a0 += zv * ldsD[f * 16 + hs * 2];
                        a1 += zv * ldsD[f * 16 + hs * 2 + 1];
                    }
                    if (tt == 0) { s0[0] = a0; s0[1] = a1; }
                    else if (tt == 1) { s1[0] = a0; s1[1] = a1; }
                    else { s2[0] = a0; s2[1] = a1; }
                }
                #pragma unroll
                for (int e = 0; e < 2; e++) {
                    int h = h0 + hs * 2 + e;
                    pr[g][e] = s0[e] * g_xWxT[(g * 1024 + h) * 64 + b]
                             + s1[e] * (g_hWhP[(g * 1024 + h) * 64 + b]
                                      + g_hWhP[262144 + (g * 1024 + h) * 64 + b])
                             + s2[e] + b0w[g * 1024 + h];
                }
            }
            #pragma unroll
            for (int e = 0; e < 2; e++) {
                int h = h0 + hs * 2 + e;
                float cv = g_cT[h * 64 + b];
                float nc = sigf(pr[1][e]) * cv + sigf(pr[0][e]) * tanhf(pr[2][e]);
                float nh = sigf(pr[3][e]) * tanhf(nc);
                g_cT[h * 64 + b] = nc;
                g_hT[h * 64 + b] = nh;
            }
        }
        grid.sync();   // s3
    }
}

// ---------------------------------------------------------------------------
extern "C" void kernel_launch(void* const* d_in, const int* in_sizes, int n_in,
                              void* d_out, int out_size, void* d_ws, size_t ws_size,
                              hipStream_t stream)
{
    const float* z         = (const float*)d_in[0];
    const float* strokes   = (const float*)d_in[1];
    const float* fc_in_w   = (const float*)d_in[2];
    const float* fc_in_b   = (const float*)d_in[3];
    const float* fc_proj_w = (const float*)d_in[4];
    const float* fc_proj_b = (const float*)d_in[5];
    const float* Wx        = (const float*)d_in[6];
    const float* Wh        = (const float*)d_in[7];
    const float* b0w       = (const float*)d_in[8];
    const float* Wxh_hy    = (const float*)d_in[9];
    const float* Whh_hy    = (const float*)d_in[10];
    const float* b_hy      = (const float*)d_in[11];
    const float* Wzx       = (const float*)d_in[12];
    const float* bzx       = (const float*)d_in[13];
    const float* Wzh       = (const float*)d_in[14];
    const float* bzh       = (const float*)d_in[15];
    const float* Wzb       = (const float*)d_in[16];
    const float* Dx        = (const float*)d_in[17];
    const float* Dh        = (const float*)d_in[18];
    const float* Db        = (const float*)d_in[19];
    (void)d_ws; (void)ws_size;
    float* out = (float*)d_out;

    void* args[] = {
        (void*)&z, (void*)&strokes, (void*)&fc_in_w, (void*)&fc_in_b,
        (void*)&fc_proj_w, (void*)&fc_proj_b, (void*)&Wx, (void*)&Wh,
        (void*)&b0w, (void*)&Wxh_hy, (void*)&Whh_hy, (void*)&b_hy,
        (void*)&Wzx, (void*)&bzx, (void*)&Wzh, (void*)&bzh, (void*)&Wzb,
        (void*)&Dx, (void*)&Dh, (void*)&Db, (void*)&out
    };
    hipLaunchCooperativeKernel((const void*)mega_kernel,
                               dim3(256), dim3(512), args, 0, stream);
}